// Round 3
// baseline (385.768 us; speedup 1.0000x reference)
//
#include <hip/hip_runtime.h>
#include <hip/hip_cooperative_groups.h>

namespace cg = cooperative_groups;

#define D 128
#define CAP 64
#define OVF_CAP 1024

typedef short bf16x8 __attribute__((ext_vector_type(8)));
typedef float f32x4 __attribute__((ext_vector_type(4)));

__device__ __forceinline__ unsigned short f2bf(float f) {
  unsigned u = __builtin_bit_cast(unsigned, f);
  unsigned r = (u + 0x7fffu + ((u >> 16) & 1u)) >> 16;
  return (unsigned short)r;
}
__device__ __forceinline__ float bflo(unsigned r) {
  return __builtin_bit_cast(float, r << 16);
}
__device__ __forceinline__ float bfhi(unsigned r) {
  return __builtin_bit_cast(float, r & 0xffff0000u);
}
__device__ __forceinline__ float lrelu(float t) {
  return t >= 0.f ? t : 0.2f * t;
}
// LDS byte-offset swizzle: XOR bits 8-10 into bits 4-6 (write side spreads a
// fixed row's 64 lanes over all banks; read stays full-coverage b128).
__device__ __forceinline__ int swz(int b) { return b ^ (((b >> 8) & 7) << 4); }

// ============================================================
// Mega-kernel: all 5 phases with grid-wide syncs (cooperative)
// ============================================================

struct Params {
  const int *s, *eiP, *eiC, *eiR;
  const float *emb;
  const float *Wp, *asp, *adp, *bp;
  const float *Wc, *asc, *adc, *bc;
  const float *Wl, *bl, *Wr;
  float *out;
  float *a_sp, *a_dp, *a_sc, *a_dc, *selfP, *selfC;
  int *qid;
  unsigned *ebf;
  int *uniq, *counters;
  float *vvec;
  unsigned short *wpack;
  float *outU;
  int *degP, *degC, *degR;
  float *denP, *denC;
  int2 *bktP, *bktC;
  int *bktR;
  int2 *ovf;
  int S, E, N;
};

__global__ void __launch_bounds__(512) k_mega(Params p) {
  cg::grid_group gg = cg::this_grid();
  __shared__ __align__(16) unsigned short A_lds[16 * 64 * 8];   // 16 KB
  const int tid = threadIdx.x;
  const int lane = tid & 63;
  const int gtid = blockIdx.x * 512 + tid;
  const int gstride = gridDim.x * 512;

  // ---------- Phase A: init + wpack + vvec ----------
  for (int k = gtid; k < p.N; k += gstride) p.qid[k] = -1;
  for (int k = gtid; k < 5 * p.S; k += gstride) p.degP[k] = 0;  // deg/den contiguous
  if (gtid < 16) p.counters[gtid] = 0;

  for (int idx = gtid; idx < 16 * 8 * 64 * 8; idx += gstride) {
    int j   = idx & 7;
    int ln2 = (idx >> 3) & 63;
    int nt  = (idx >> 9) & 7;
    int kt  = idx >> 12;
    int o = kt >> 2;
    int c = (kt & 3) * 32 + (ln2 >> 4) * 8 + j;
    int n = nt * 16 + (ln2 & 15);
    const float* W = (o == 0) ? p.Wp : (o == 1) ? p.Wc : (o == 2) ? p.Wl : p.Wr;
    p.wpack[idx] = f2bf(W[c * D + n]);
  }

  if (gtid < 4096) {               // 128 rows x 32 lanes: v[0..4D)
    int k = gtid >> 5, ln = gtid & 31;
    float4 as4p = ((const float4*)p.asp)[ln];
    float4 ad4p = ((const float4*)p.adp)[ln];
    float4 as4c = ((const float4*)p.asc)[ln];
    float4 ad4c = ((const float4*)p.adc)[ln];
    float4 wp4 = ((const float4*)(p.Wp + (size_t)k * D))[ln];
    float4 wc4 = ((const float4*)(p.Wc + (size_t)k * D))[ln];
    float s0 = wp4.x * as4p.x + wp4.y * as4p.y + wp4.z * as4p.z + wp4.w * as4p.w;
    float s1 = wp4.x * ad4p.x + wp4.y * ad4p.y + wp4.z * ad4p.z + wp4.w * ad4p.w;
    float s2 = wc4.x * as4c.x + wc4.y * as4c.y + wc4.z * as4c.z + wc4.w * as4c.w;
    float s3 = wc4.x * ad4c.x + wc4.y * ad4c.y + wc4.z * ad4c.z + wc4.w * ad4c.w;
#pragma unroll
    for (int o = 16; o > 0; o >>= 1) {
      s0 += __shfl_down(s0, o, 32);
      s1 += __shfl_down(s1, o, 32);
      s2 += __shfl_down(s2, o, 32);
      s3 += __shfl_down(s3, o, 32);
    }
    if (ln == 0) {
      p.vvec[k] = s0; p.vvec[D + k] = s1;
      p.vvec[2 * D + k] = s2; p.vvec[3 * D + k] = s3;
    }
  } else if (gtid < 4096 + 128) {
    int k = gtid - 4096;
    p.vvec[4 * D + k] = p.bp[k] + p.bc[k] + p.bl[k];
  }
  gg.sync();

  // ---------- Phase B: qid build + attention scalars + bf16 emb ----------
  for (int q = gtid; q < p.S; q += gstride) {
    int n = p.s[q];
    bool won = (atomicCAS(&p.qid[n], -1, -2) == -1);
    unsigned long long mask = __ballot(won);
    if (mask != 0ull) {
      int leader = __builtin_ctzll(mask);
      int base = 0;
      if (lane == leader) base = atomicAdd(&p.counters[0], __popcll(mask));
      base = __shfl(base, leader);
      if (won) {
        int u = base + __popcll(mask & ((1ull << lane) - 1ull));
        p.uniq[u] = n;
        p.qid[n] = u;
      }
    }
  }
  const int nodeSlots = ((p.N + 1) >> 1) * 64;   // wave-uniform bound
  for (int idx = gtid; idx < nodeSlots; idx += gstride) {
    int node = (idx >> 6) * 2 + ((idx & 63) >> 5);
    int c = idx & 31;
    if (node < p.N) {
      float4 x4 = ((const float4*)(p.emb + (size_t)node * D))[c];
      uint2 pk;
      pk.x = ((unsigned)f2bf(x4.x)) | (((unsigned)f2bf(x4.y)) << 16);
      pk.y = ((unsigned)f2bf(x4.z)) | (((unsigned)f2bf(x4.w)) << 16);
      ((uint2*)p.ebf)[(size_t)node * 32 + c] = pk;
      float4 v0 = ((const float4*)(p.vvec))[c];
      float4 v1 = ((const float4*)(p.vvec + D))[c];
      float4 v2 = ((const float4*)(p.vvec + 2 * D))[c];
      float4 v3 = ((const float4*)(p.vvec + 3 * D))[c];
      float s0 = x4.x * v0.x + x4.y * v0.y + x4.z * v0.z + x4.w * v0.w;
      float s1 = x4.x * v1.x + x4.y * v1.y + x4.z * v1.z + x4.w * v1.w;
      float s2 = x4.x * v2.x + x4.y * v2.y + x4.z * v2.z + x4.w * v2.w;
      float s3 = x4.x * v3.x + x4.y * v3.y + x4.z * v3.z + x4.w * v3.w;
#pragma unroll
      for (int o = 16; o > 0; o >>= 1) {
        s0 += __shfl_down(s0, o);
        s1 += __shfl_down(s1, o);
        s2 += __shfl_down(s2, o);
        s3 += __shfl_down(s3, o);
      }
      if (c == 0) {
        p.a_sp[node] = s0; p.a_dp[node] = s1;
        p.a_sc[node] = s2; p.a_dc[node] = s3;
        p.selfP[node] = __expf(lrelu(s0 + s1));
        p.selfC[node] = __expf(lrelu(s2 + s3));
      }
    }
  }
  gg.sync();

  // ---------- Phase C: edge filter + weights + denominators ----------
  for (int e3 = gtid; e3 < 3 * p.E; e3 += gstride) {
    int rel = (e3 >= 2 * p.E) ? 2 : (e3 >= p.E) ? 1 : 0;
    int e = e3 - rel * p.E;
    const int* ei = (rel == 0) ? p.eiP : (rel == 1) ? p.eiC : p.eiR;
    int dst = ei[p.E + e];
    int u = p.qid[dst];
    if (u < 0) continue;
    int src = ei[e];
    int* deg = (rel == 0) ? p.degP : (rel == 1) ? p.degC : p.degR;
    int pos = atomicAdd(&deg[u], 1);
    if (rel == 2) {
      if (pos < CAP) {
        p.bktR[u * CAP + pos] = src;
      } else {
        int o = atomicAdd(&p.counters[6], 1);
        if (o < OVF_CAP) { int2 tt; tt.x = src; tt.y = u; p.ovf[2 * OVF_CAP + o] = tt; }
      }
    } else {
      const float* a_s = (rel == 0) ? p.a_sp : p.a_sc;
      const float* a_d = (rel == 0) ? p.a_dp : p.a_dc;
      float wgt = __expf(lrelu(a_s[src] + a_d[dst]));
      atomicAdd((rel == 0) ? &p.denP[u] : &p.denC[u], wgt);
      if (pos < CAP) {
        int2 tt; tt.x = src; tt.y = __builtin_bit_cast(int, wgt);
        ((rel == 0) ? p.bktP : p.bktC)[u * CAP + pos] = tt;
      } else {
        int o = atomicAdd(&p.counters[4 + rel], 1);
        if (o < OVF_CAP) { int2 tt; tt.x = src; tt.y = u; p.ovf[rel * OVF_CAP + o] = tt; }
      }
    }
  }
  gg.sync();

  // ---------- Phase D: fused gather + MFMA ----------
  int U = p.counters[0];
  int w = tid >> 6;
  int Lc[3];
#pragma unroll
  for (int r = 0; r < 3; ++r) {
    int L = p.counters[4 + r];
    Lc[r] = (L > OVF_CAP) ? OVF_CAP : L;
  }

  for (int tile = blockIdx.x; tile * 16 < U; tile += gridDim.x) {
    int u0 = tile * 16;
    __syncthreads();   // A_lds reuse guard (prev tile's reads done)
#pragma unroll
    for (int t = 0; t < 2; ++t) {
      int m = 2 * w + t;
      int u = u0 + m;
      float2 z[4];
      if (u < U) {
        int n = p.uniq[u];
        float2 x2 = ((const float2*)(p.emb + (size_t)n * D))[lane];
#pragma unroll
        for (int r = 0; r < 3; ++r) {
          int dg = ((r == 0) ? p.degP : (r == 1) ? p.degC : p.degR)[u];
          int mc = (dg < CAP) ? dg : CAP;
          int srcl = 0;
          float wl = 0.f;
          if (r < 2) {
            if (lane < mc) {
              int2 sw_ = ((r == 0) ? p.bktP : p.bktC)[u * CAP + lane];
              srcl = sw_.x;
              wl = __builtin_bit_cast(float, sw_.y);
            }
          } else {
            if (lane < mc) { srcl = p.bktR[u * CAP + lane]; wl = 1.f; }
          }
          float2 a; a.x = 0.f; a.y = 0.f;
          int i = 0;
          for (; i + 4 <= mc; i += 4) {
            int s0 = __shfl(srcl, i),     s1 = __shfl(srcl, i + 1);
            int s2 = __shfl(srcl, i + 2), s3 = __shfl(srcl, i + 3);
            float w0 = __shfl(wl, i),     w1 = __shfl(wl, i + 1);
            float w2 = __shfl(wl, i + 2), w3 = __shfl(wl, i + 3);
            unsigned r0 = p.ebf[(size_t)s0 * 64 + lane];
            unsigned r1 = p.ebf[(size_t)s1 * 64 + lane];
            unsigned r2 = p.ebf[(size_t)s2 * 64 + lane];
            unsigned r3 = p.ebf[(size_t)s3 * 64 + lane];
            a.x += w0 * bflo(r0) + w1 * bflo(r1) + w2 * bflo(r2) + w3 * bflo(r3);
            a.y += w0 * bfhi(r0) + w1 * bfhi(r1) + w2 * bfhi(r2) + w3 * bfhi(r3);
          }
          for (; i < mc; ++i) {
            int si = __shfl(srcl, i);
            float wi = __shfl(wl, i);
            unsigned rr = p.ebf[(size_t)si * 64 + lane];
            a.x += wi * bflo(rr);
            a.y += wi * bfhi(rr);
          }
          if (dg > CAP) {           // overflow fixup (statistically never)
            const float* a_s = (r == 0) ? p.a_sp : p.a_sc;
            float adn = (r == 0) ? p.a_dp[n] : (r == 1) ? p.a_dc[n] : 0.f;
            for (int l = 0; l < Lc[r]; ++l) {
              int2 ov = p.ovf[r * OVF_CAP + l];
              if (ov.y == u) {
                float wv = 1.f;
                if (r < 2) wv = __expf(lrelu(a_s[ov.x] + adn));
                unsigned rr = p.ebf[(size_t)ov.x * 64 + lane];
                a.x += wv * bflo(rr);
                a.y += wv * bfhi(rr);
              }
            }
          }
          if (r == 2) {
            float dgc = (float)dg; if (dgc < 1.f) dgc = 1.f;
            float rc = 1.f / dgc;
            a.x *= rc; a.y *= rc;
          }
          z[r] = a;
        }
        float wP = p.selfP[n];
        float rP = 1.f / (p.denP[u] + wP);
        float wC = p.selfC[n];
        float rC = 1.f / (p.denC[u] + wC);
        z[0].x = (z[0].x + wP * x2.x) * rP; z[0].y = (z[0].y + wP * x2.y) * rP;
        z[1].x = (z[1].x + wC * x2.x) * rC; z[1].y = (z[1].y + wC * x2.y) * rC;
        z[3] = x2;
      } else {
        z[0].x = 0.f; z[0].y = 0.f; z[1] = z[0]; z[2] = z[0]; z[3] = z[0];
      }
      int ktc = lane >> 4;
      int q = (lane >> 2) & 3;
      int j0 = 2 * (lane & 3);
#pragma unroll
      for (int o = 0; o < 4; ++o) {
        int kt = o * 4 + ktc;
        unsigned pk = ((unsigned)f2bf(z[o].x)) | (((unsigned)f2bf(z[o].y)) << 16);
        int off = ((kt * 64 + q * 16 + m) * 8 + j0) * 2;
        *(unsigned*)((char*)A_lds + swz(off)) = pk;
      }
    }
    __syncthreads();

    f32x4 acc = {0.f, 0.f, 0.f, 0.f};
    const bf16x8* wp = (const bf16x8*)p.wpack;
#pragma unroll
    for (int kt = 0; kt < 16; ++kt) {
      bf16x8 a = *(const bf16x8*)((const char*)A_lds + swz((kt * 64 + lane) * 16));
      bf16x8 b = wp[(kt * 8 + w) * 64 + lane];
      acc = __builtin_amdgcn_mfma_f32_16x16x32_bf16(a, b, acc, 0, 0, 0);
    }

    int col = w * 16 + (lane & 15);
    int r0 = (lane >> 4) * 4;
    float bv = p.vvec[4 * D + col] * (1.f / 3.f);
#pragma unroll
    for (int reg = 0; reg < 4; ++reg) {
      int u = u0 + r0 + reg;
      if (u < U) p.outU[(size_t)u * D + col] = acc[reg] * (1.f / 3.f) + bv;
    }
  }
  gg.sync();

  // ---------- Phase E: gather ----------
  for (int idx = gtid; idx < p.S * 32; idx += gstride) {
    int i = idx >> 5;
    int c = idx & 31;
    int u = p.qid[p.s[i]];
    ((float4*)p.out)[idx] = ((const float4*)p.outU)[(size_t)u * 32 + c];
  }
}

// ============================================================
// Legacy 5-kernel path (fallback if cooperative launch fails)
// ============================================================

__global__ void k_setup(const float* __restrict__ Wp, const float* __restrict__ asp,
                        const float* __restrict__ adp, const float* __restrict__ Wc,
                        const float* __restrict__ asc, const float* __restrict__ adc,
                        const float* __restrict__ bp, const float* __restrict__ bc,
                        const float* __restrict__ bl, const float* __restrict__ Wl,
                        const float* __restrict__ Wr,
                        float* __restrict__ v, unsigned short* __restrict__ wpack,
                        int* __restrict__ qid, int* __restrict__ counters,
                        int* __restrict__ deg5, int N, int S5) {
  int i = blockIdx.x * blockDim.x + threadIdx.x;
  int stride = gridDim.x * blockDim.x;
  for (int k = i; k < N; k += stride) qid[k] = -1;
  for (int k = i; k < S5; k += stride) deg5[k] = 0;
  if (i < 16) counters[i] = 0;
  for (int idx = i; idx < 16 * 8 * 64 * 8; idx += stride) {
    int j    = idx & 7;
    int lane = (idx >> 3) & 63;
    int nt   = (idx >> 9) & 7;
    int kt   = idx >> 12;
    int o = kt >> 2;
    int c = (kt & 3) * 32 + (lane >> 4) * 8 + j;
    int n = nt * 16 + (lane & 15);
    const float* W = (o == 0) ? Wp : (o == 1) ? Wc : (o == 2) ? Wl : Wr;
    wpack[idx] = f2bf(W[c * D + n]);
  }
  if (blockIdx.x == 0) {
    int hw = threadIdx.x >> 5;
    int ln = threadIdx.x & 31;
    float4 as4p = ((const float4*)asp)[ln];
    float4 ad4p = ((const float4*)adp)[ln];
    float4 as4c = ((const float4*)asc)[ln];
    float4 ad4c = ((const float4*)adc)[ln];
    for (int k = hw; k < D; k += 8) {
      float4 wp4 = ((const float4*)(Wp + (size_t)k * D))[ln];
      float4 wc4 = ((const float4*)(Wc + (size_t)k * D))[ln];
      float s0 = wp4.x * as4p.x + wp4.y * as4p.y + wp4.z * as4p.z + wp4.w * as4p.w;
      float s1 = wp4.x * ad4p.x + wp4.y * ad4p.y + wp4.z * ad4p.z + wp4.w * ad4p.w;
      float s2 = wc4.x * as4c.x + wc4.y * as4c.y + wc4.z * as4c.z + wc4.w * as4c.w;
      float s3 = wc4.x * ad4c.x + wc4.y * ad4c.y + wc4.z * ad4c.z + wc4.w * ad4c.w;
#pragma unroll
      for (int o = 16; o > 0; o >>= 1) {
        s0 += __shfl_down(s0, o, 32);
        s1 += __shfl_down(s1, o, 32);
        s2 += __shfl_down(s2, o, 32);
        s3 += __shfl_down(s3, o, 32);
      }
      if (ln == 0) { v[k] = s0; v[D + k] = s1; v[2 * D + k] = s2; v[3 * D + k] = s3; }
    }
    if (threadIdx.x < D) {
      int k = threadIdx.x;
      v[4 * D + k] = bp[k] + bc[k] + bl[k];
    }
  }
}

__global__ void k_pre(const int* __restrict__ s, int* __restrict__ qid,
                      int* __restrict__ uniq, int* __restrict__ counters, int S,
                      const float* __restrict__ emb, const float* __restrict__ v,
                      float* __restrict__ a_sp, float* __restrict__ a_dp,
                      float* __restrict__ a_sc, float* __restrict__ a_dc,
                      float* __restrict__ selfP, float* __restrict__ selfC,
                      unsigned* __restrict__ ebf, int N) {
  int gtid = blockIdx.x * blockDim.x + threadIdx.x;
  int lane = threadIdx.x & 63;
  if (gtid < S) {
    int n = s[gtid];
    bool won = (atomicCAS(&qid[n], -1, -2) == -1);
    unsigned long long mask = __ballot(won);
    if (mask != 0ull) {
      int leader = __builtin_ctzll(mask);
      int base = 0;
      if (lane == leader) base = atomicAdd(&counters[0], __popcll(mask));
      base = __shfl(base, leader);
      if (won) {
        int u = base + __popcll(mask & ((1ull << lane) - 1ull));
        uniq[u] = n;
        qid[n] = u;
      }
    }
  }
  int node = (gtid >> 6) * 2 + (lane >> 5);
  int c = lane & 31;
  if (node >= N) return;
  float4 x4 = ((const float4*)(emb + (size_t)node * D))[c];
  uint2 p;
  p.x = ((unsigned)f2bf(x4.x)) | (((unsigned)f2bf(x4.y)) << 16);
  p.y = ((unsigned)f2bf(x4.z)) | (((unsigned)f2bf(x4.w)) << 16);
  ((uint2*)ebf)[(size_t)node * 32 + c] = p;
  float4 v0 = ((const float4*)(v))[c];
  float4 v1 = ((const float4*)(v + D))[c];
  float4 v2 = ((const float4*)(v + 2 * D))[c];
  float4 v3 = ((const float4*)(v + 3 * D))[c];
  float s0 = x4.x * v0.x + x4.y * v0.y + x4.z * v0.z + x4.w * v0.w;
  float s1 = x4.x * v1.x + x4.y * v1.y + x4.z * v1.z + x4.w * v1.w;
  float s2 = x4.x * v2.x + x4.y * v2.y + x4.z * v2.z + x4.w * v2.w;
  float s3 = x4.x * v3.x + x4.y * v3.y + x4.z * v3.z + x4.w * v3.w;
#pragma unroll
  for (int o = 16; o > 0; o >>= 1) {
    s0 += __shfl_down(s0, o);
    s1 += __shfl_down(s1, o);
    s2 += __shfl_down(s2, o);
    s3 += __shfl_down(s3, o);
  }
  if (c == 0) {
    a_sp[node] = s0; a_dp[node] = s1; a_sc[node] = s2; a_dc[node] = s3;
    selfP[node] = __expf(lrelu(s0 + s1));
    selfC[node] = __expf(lrelu(s2 + s3));
  }
}

__global__ void __launch_bounds__(256) k_filter(
    const int* __restrict__ eiP, const int* __restrict__ eiC,
    const int* __restrict__ eiR, const int* __restrict__ qid,
    int2* __restrict__ bktP, int2* __restrict__ bktC, int* __restrict__ bktR,
    int* __restrict__ degP, int* __restrict__ degC, int* __restrict__ degR,
    float* __restrict__ denP, float* __restrict__ denC,
    const float* __restrict__ a_sp, const float* __restrict__ a_dp,
    const float* __restrict__ a_sc, const float* __restrict__ a_dc,
    int2* __restrict__ ovf, int* __restrict__ counters, int E) {
  int rel = blockIdx.y;
  const int* ei = (rel == 0) ? eiP : (rel == 1) ? eiC : eiR;
  int e = blockIdx.x * 256 + threadIdx.x;
  if (e >= E) return;
  int dst = ei[E + e];
  int u = qid[dst];
  if (u < 0) return;
  int src = ei[e];
  int* deg = (rel == 0) ? degP : (rel == 1) ? degC : degR;
  int pos = atomicAdd(&deg[u], 1);
  if (rel == 2) {
    if (pos < CAP) {
      bktR[u * CAP + pos] = src;
    } else {
      int o = atomicAdd(&counters[6], 1);
      if (o < OVF_CAP) { int2 tt; tt.x = src; tt.y = u; ovf[2 * OVF_CAP + o] = tt; }
    }
  } else {
    const float* a_s = (rel == 0) ? a_sp : a_sc;
    const float* a_d = (rel == 0) ? a_dp : a_dc;
    float wgt = __expf(lrelu(a_s[src] + a_d[dst]));
    atomicAdd((rel == 0) ? &denP[u] : &denC[u], wgt);
    if (pos < CAP) {
      int2 tt; tt.x = src; tt.y = __builtin_bit_cast(int, wgt);
      ((rel == 0) ? bktP : bktC)[u * CAP + pos] = tt;
    } else {
      int o = atomicAdd(&counters[4 + rel], 1);
      if (o < OVF_CAP) { int2 tt; tt.x = src; tt.y = u; ovf[rel * OVF_CAP + o] = tt; }
    }
  }
}

__global__ void __launch_bounds__(512) k_fused(
    const int2* __restrict__ bktP, const int2* __restrict__ bktC,
    const int* __restrict__ bktR,
    const int* __restrict__ degP, const int* __restrict__ degC,
    const int* __restrict__ degR,
    const float* __restrict__ denP, const float* __restrict__ denC,
    const float* __restrict__ a_sp, const float* __restrict__ a_dp,
    const float* __restrict__ a_sc, const float* __restrict__ a_dc,
    const float* __restrict__ selfP, const float* __restrict__ selfC,
    const unsigned* __restrict__ ebf, const float* __restrict__ emb,
    const int* __restrict__ uniq, const int* __restrict__ counters,
    const int2* __restrict__ ovf, const float* __restrict__ vvec,
    const unsigned short* __restrict__ wpack, float* __restrict__ outU) {
  __shared__ __align__(16) unsigned short A_lds[16 * 64 * 8];
  int U = counters[0];
  int u0 = blockIdx.x * 16;
  if (u0 >= U) return;
  int tid = threadIdx.x;
  int w = tid >> 6;
  int lane = tid & 63;
  int Lc[3];
#pragma unroll
  for (int r = 0; r < 3; ++r) {
    int L = counters[4 + r];
    Lc[r] = (L > OVF_CAP) ? OVF_CAP : L;
  }
#pragma unroll
  for (int t = 0; t < 2; ++t) {
    int m = 2 * w + t;
    int u = u0 + m;
    float2 z[4];
    if (u < U) {
      int n = uniq[u];
      float2 x2 = ((const float2*)(emb + (size_t)n * D))[lane];
#pragma unroll
      for (int r = 0; r < 3; ++r) {
        int dg = ((r == 0) ? degP : (r == 1) ? degC : degR)[u];
        int mc = (dg < CAP) ? dg : CAP;
        int srcl = 0;
        float wl = 0.f;
        if (r < 2) {
          if (lane < mc) {
            int2 sw_ = ((r == 0) ? bktP : bktC)[u * CAP + lane];
            srcl = sw_.x;
            wl = __builtin_bit_cast(float, sw_.y);
          }
        } else {
          if (lane < mc) { srcl = bktR[u * CAP + lane]; wl = 1.f; }
        }
        float2 a; a.x = 0.f; a.y = 0.f;
        int i = 0;
        for (; i + 4 <= mc; i += 4) {
          int s0 = __shfl(srcl, i),     s1 = __shfl(srcl, i + 1);
          int s2 = __shfl(srcl, i + 2), s3 = __shfl(srcl, i + 3);
          float w0 = __shfl(wl, i),     w1 = __shfl(wl, i + 1);
          float w2 = __shfl(wl, i + 2), w3 = __shfl(wl, i + 3);
          unsigned r0 = ebf[(size_t)s0 * 64 + lane];
          unsigned r1 = ebf[(size_t)s1 * 64 + lane];
          unsigned r2 = ebf[(size_t)s2 * 64 + lane];
          unsigned r3 = ebf[(size_t)s3 * 64 + lane];
          a.x += w0 * bflo(r0) + w1 * bflo(r1) + w2 * bflo(r2) + w3 * bflo(r3);
          a.y += w0 * bfhi(r0) + w1 * bfhi(r1) + w2 * bfhi(r2) + w3 * bfhi(r3);
        }
        for (; i < mc; ++i) {
          int si = __shfl(srcl, i);
          float wi = __shfl(wl, i);
          unsigned rr = ebf[(size_t)si * 64 + lane];
          a.x += wi * bflo(rr);
          a.y += wi * bfhi(rr);
        }
        if (dg > CAP) {
          const float* a_s = (r == 0) ? a_sp : a_sc;
          float adn = (r == 0) ? a_dp[n] : (r == 1) ? a_dc[n] : 0.f;
          for (int l = 0; l < Lc[r]; ++l) {
            int2 ov = ovf[r * OVF_CAP + l];
            if (ov.y == u) {
              float wv = 1.f;
              if (r < 2) wv = __expf(lrelu(a_s[ov.x] + adn));
              unsigned rr = ebf[(size_t)ov.x * 64 + lane];
              a.x += wv * bflo(rr);
              a.y += wv * bfhi(rr);
            }
          }
        }
        if (r == 2) {
          float dgc = (float)dg; if (dgc < 1.f) dgc = 1.f;
          float rc = 1.f / dgc;
          a.x *= rc; a.y *= rc;
        }
        z[r] = a;
      }
      float wP = selfP[n];
      float rP = 1.f / (denP[u] + wP);
      float wC = selfC[n];
      float rC = 1.f / (denC[u] + wC);
      z[0].x = (z[0].x + wP * x2.x) * rP; z[0].y = (z[0].y + wP * x2.y) * rP;
      z[1].x = (z[1].x + wC * x2.x) * rC; z[1].y = (z[1].y + wC * x2.y) * rC;
      z[3] = x2;
    } else {
      z[0].x = 0.f; z[0].y = 0.f; z[1] = z[0]; z[2] = z[0]; z[3] = z[0];
    }
    int ktc = lane >> 4;
    int q = (lane >> 2) & 3;
    int j0 = 2 * (lane & 3);
#pragma unroll
    for (int o = 0; o < 4; ++o) {
      int kt = o * 4 + ktc;
      unsigned pk = ((unsigned)f2bf(z[o].x)) | (((unsigned)f2bf(z[o].y)) << 16);
      int off = ((kt * 64 + q * 16 + m) * 8 + j0) * 2;
      *(unsigned*)((char*)A_lds + swz(off)) = pk;
    }
  }
  __syncthreads();
  f32x4 acc = {0.f, 0.f, 0.f, 0.f};
  const bf16x8* wp = (const bf16x8*)wpack;
#pragma unroll
  for (int kt = 0; kt < 16; ++kt) {
    bf16x8 a = *(const bf16x8*)((const char*)A_lds + swz((kt * 64 + lane) * 16));
    bf16x8 b = wp[(kt * 8 + w) * 64 + lane];
    acc = __builtin_amdgcn_mfma_f32_16x16x32_bf16(a, b, acc, 0, 0, 0);
  }
  int col = w * 16 + (lane & 15);
  int r0 = (lane >> 4) * 4;
  float bv = vvec[4 * D + col] * (1.f / 3.f);
#pragma unroll
  for (int reg = 0; reg < 4; ++reg) {
    int u = u0 + r0 + reg;
    if (u < U) outU[(size_t)u * D + col] = acc[reg] * (1.f / 3.f) + bv;
  }
}

__global__ void k_gather(const int* __restrict__ s, const int* __restrict__ qid,
                         const float4* __restrict__ outU4, float4* __restrict__ out4,
                         int S) {
  int idx = blockIdx.x * blockDim.x + threadIdx.x;
  if (idx >= S * 32) return;
  int i = idx >> 5;
  int c = idx & 31;
  int u = qid[s[i]];
  out4[idx] = outU4[(size_t)u * 32 + c];
}

// ---------------- launch ----------------

extern "C" void kernel_launch(void* const* d_in, const int* in_sizes, int n_in,
                              void* d_out, int out_size, void* d_ws, size_t ws_size,
                              hipStream_t stream) {
  const int*   s   = (const int*)d_in[0];
  const int*   eip = (const int*)d_in[3];
  const int*   eic = (const int*)d_in[4];
  const int*   eir = (const int*)d_in[5];
  const float* emb = (const float*)d_in[6];
  const float* Wp  = (const float*)d_in[7];
  const float* asp = (const float*)d_in[8];
  const float* adp = (const float*)d_in[9];
  const float* bp  = (const float*)d_in[10];
  const float* Wc  = (const float*)d_in[11];
  const float* asc = (const float*)d_in[12];
  const float* adc = (const float*)d_in[13];
  const float* bc  = (const float*)d_in[14];
  const float* Wl  = (const float*)d_in[15];
  const float* bl  = (const float*)d_in[16];
  const float* Wr  = (const float*)d_in[17];
  float* out = (float*)d_out;

  const int S = in_sizes[0];
  const int E = in_sizes[3] / 2;
  const int N = in_sizes[6] / D;

  char* base = (char*)d_ws;
  size_t off = 0;
  auto carve = [&](size_t bytes) -> char* {
    char* q = base + off;
    off += (bytes + 255) & ~(size_t)255;
    return q;
  };
  float*    a_sp     = (float*)carve((size_t)N * 4);
  float*    a_dp     = (float*)carve((size_t)N * 4);
  float*    a_sc     = (float*)carve((size_t)N * 4);
  float*    a_dc     = (float*)carve((size_t)N * 4);
  float*    selfP    = (float*)carve((size_t)N * 4);
  float*    selfC    = (float*)carve((size_t)N * 4);
  int*      qid      = (int*)carve((size_t)N * 4);
  unsigned* ebf      = (unsigned*)carve((size_t)N * 64 * 4);
  int*      uniq     = (int*)carve((size_t)S * 4);
  int*      counters = (int*)carve(64);
  float*    vvec     = (float*)carve(5 * D * 4);
  unsigned short* wpack = (unsigned short*)carve((size_t)16 * 8 * 64 * 8 * 2);
  float*    outU     = (float*)carve((size_t)S * D * 4);
  int*      degP     = (int*)carve((size_t)S * 4);
  int*      degC     = (int*)carve((size_t)S * 4);
  int*      degR     = (int*)carve((size_t)S * 4);
  float*    denP     = (float*)carve((size_t)S * 4);
  float*    denC     = (float*)carve((size_t)S * 4);
  int2*     bktP     = (int2*)carve((size_t)S * CAP * 8);
  int2*     bktC     = (int2*)carve((size_t)S * CAP * 8);
  int*      bktR     = (int*)carve((size_t)S * CAP * 4);
  int2*     ovf      = (int2*)carve((size_t)3 * OVF_CAP * 8);
  (void)ws_size; (void)n_in; (void)out_size;

  Params P;
  P.s = s; P.eiP = eip; P.eiC = eic; P.eiR = eir; P.emb = emb;
  P.Wp = Wp; P.asp = asp; P.adp = adp; P.bp = bp;
  P.Wc = Wc; P.asc = asc; P.adc = adc; P.bc = bc;
  P.Wl = Wl; P.bl = bl; P.Wr = Wr;
  P.out = out;
  P.a_sp = a_sp; P.a_dp = a_dp; P.a_sc = a_sc; P.a_dc = a_dc;
  P.selfP = selfP; P.selfC = selfC;
  P.qid = qid; P.ebf = ebf; P.uniq = uniq; P.counters = counters;
  P.vvec = vvec; P.wpack = wpack; P.outU = outU;
  P.degP = degP; P.degC = degC; P.degR = degR;
  P.denP = denP; P.denC = denC;
  P.bktP = bktP; P.bktC = bktC; P.bktR = bktR; P.ovf = ovf;
  P.S = S; P.E = E; P.N = N;

  // Co-resident grid sizing (host-side queries only; cached)
  static int gridBlocks = 0;
  if (gridBlocks == 0) {
    int nb = 0;
    hipOccupancyMaxActiveBlocksPerMultiprocessor(&nb, k_mega, 512, 0);
    if (nb < 1) nb = 1;
    int dev = 0;
    hipGetDevice(&dev);
    hipDeviceProp_t prop;
    int cus = 256;
    if (hipGetDeviceProperties(&prop, dev) == hipSuccess && prop.multiProcessorCount > 0)
      cus = prop.multiProcessorCount;
    gridBlocks = nb * cus;
  }

  void* args[] = {(void*)&P};
  hipError_t err = hipLaunchCooperativeKernel(k_mega, dim3(gridBlocks), dim3(512),
                                              args, 0, stream);
  if (err != hipSuccess) {
    // Fallback: proven 5-kernel path
    k_setup<<<256, 256, 0, stream>>>(Wp, asp, adp, Wc, asc, adc, bp, bc, bl, Wl, Wr,
                                     vvec, wpack, qid, counters, degP, N, 5 * S);
    k_pre<<<(N * 32 + 255) / 256, 256, 0, stream>>>(s, qid, uniq, counters, S,
                                                    emb, vvec, a_sp, a_dp, a_sc, a_dc,
                                                    selfP, selfC, ebf, N);
    k_filter<<<dim3((E + 255) / 256, 3), 256, 0, stream>>>(
        eip, eic, eir, qid, bktP, bktC, bktR, degP, degC, degR, denP, denC,
        a_sp, a_dp, a_sc, a_dc, ovf, counters, E);
    k_fused<<<(S + 15) / 16, 512, 0, stream>>>(
        bktP, bktC, bktR, degP, degC, degR, denP, denC,
        a_sp, a_dp, a_sc, a_dc, selfP, selfC, ebf, emb, uniq, counters, ovf,
        vvec, wpack, outU);
    k_gather<<<(S * 32 + 255) / 256, 256, 0, stream>>>(s, qid, (const float4*)outU,
                                                       (float4*)out, S);
  }
}

// Round 4
// 209.389 us; speedup vs baseline: 1.8423x; 1.8423x over previous
//
#include <hip/hip_runtime.h>

#define D 128
#define CAP 64
#define OVF_CAP 1024

typedef short bf16x8 __attribute__((ext_vector_type(8)));
typedef float f32x4 __attribute__((ext_vector_type(4)));

__device__ __forceinline__ unsigned short f2bf(float f) {
  unsigned u = __builtin_bit_cast(unsigned, f);
  unsigned r = (u + 0x7fffu + ((u >> 16) & 1u)) >> 16;
  return (unsigned short)r;
}
__device__ __forceinline__ float lrelu(float t) {
  return t >= 0.f ? t : 0.2f * t;
}
// LDS byte-offset swizzle: XOR bits 8-10 into bits 4-6 (write side spreads a
// fixed row's 64 lanes over all banks; read stays full-coverage b128).
__device__ __forceinline__ int swz(int b) { return b ^ (((b >> 8) & 7) << 4); }

// ---------------- kernels ----------------

// setup: qid=-1, deg/den=0, counters=0, pack Wcat->bf16 fragments, calc_v (block 0,
// coalesced: half-wave per row, width-32 shfl reduce)
__global__ void k_setup(const float* __restrict__ Wp, const float* __restrict__ asp,
                        const float* __restrict__ adp, const float* __restrict__ Wc,
                        const float* __restrict__ asc, const float* __restrict__ adc,
                        const float* __restrict__ bp, const float* __restrict__ bc,
                        const float* __restrict__ bl, const float* __restrict__ Wl,
                        const float* __restrict__ Wr,
                        float* __restrict__ v, unsigned short* __restrict__ wpack,
                        int* __restrict__ qid, int* __restrict__ counters,
                        int* __restrict__ deg5, int N, int S5) {
  int i = blockIdx.x * blockDim.x + threadIdx.x;
  int stride = gridDim.x * blockDim.x;
  for (int k = i; k < N; k += stride) qid[k] = -1;
  for (int k = i; k < S5; k += stride) deg5[k] = 0;   // degP/C/R + denP/denC (0.0f bits)
  if (i < 16) counters[i] = 0;

  // wpack[((kt*8+nt)*64+lane)*8+j] = Wcat[kt*32+(lane>>4)*8+j][nt*16+(lane&15)]
  for (int idx = i; idx < 16 * 8 * 64 * 8; idx += stride) {
    int j    = idx & 7;
    int lane = (idx >> 3) & 63;
    int nt   = (idx >> 9) & 7;
    int kt   = idx >> 12;
    int o = kt >> 2;
    int c = (kt & 3) * 32 + (lane >> 4) * 8 + j;
    int n = nt * 16 + (lane & 15);
    const float* W = (o == 0) ? Wp : (o == 1) ? Wc : (o == 2) ? Wl : Wr;
    wpack[idx] = f2bf(W[c * D + n]);
  }

  if (blockIdx.x == 0) {
    int hw = threadIdx.x >> 5;       // half-wave id 0..7
    int ln = threadIdx.x & 31;
    float4 as4p = ((const float4*)asp)[ln];
    float4 ad4p = ((const float4*)adp)[ln];
    float4 as4c = ((const float4*)asc)[ln];
    float4 ad4c = ((const float4*)adc)[ln];
    for (int k = hw; k < D; k += 8) {
      float4 wp4 = ((const float4*)(Wp + (size_t)k * D))[ln];  // coalesced row
      float4 wc4 = ((const float4*)(Wc + (size_t)k * D))[ln];
      float s0 = wp4.x * as4p.x + wp4.y * as4p.y + wp4.z * as4p.z + wp4.w * as4p.w;
      float s1 = wp4.x * ad4p.x + wp4.y * ad4p.y + wp4.z * ad4p.z + wp4.w * ad4p.w;
      float s2 = wc4.x * as4c.x + wc4.y * as4c.y + wc4.z * as4c.z + wc4.w * as4c.w;
      float s3 = wc4.x * ad4c.x + wc4.y * ad4c.y + wc4.z * ad4c.z + wc4.w * ad4c.w;
#pragma unroll
      for (int o = 16; o > 0; o >>= 1) {
        s0 += __shfl_down(s0, o, 32);
        s1 += __shfl_down(s1, o, 32);
        s2 += __shfl_down(s2, o, 32);
        s3 += __shfl_down(s3, o, 32);
      }
      if (ln == 0) {
        v[k] = s0; v[D + k] = s1; v[2 * D + k] = s2; v[3 * D + k] = s3;
      }
    }
    if (threadIdx.x < D) {
      int k = threadIdx.x;
      v[4 * D + k] = bp[k] + bc[k] + bl[k];
    }
  }
}

// build_qid (wave-aggregated unique-id alloc) + attention scalars + self-loop
// weights.  Grid-strided (2048 blocks); one wave handles TWO nodes:
// 32 lanes x float4 per node row.  No bf16 emb copy anymore (gathers read emb).
__global__ void k_pre(const int* __restrict__ s, int* __restrict__ qid,
                      int* __restrict__ uniq, int* __restrict__ counters, int S,
                      const float* __restrict__ emb, const float* __restrict__ v,
                      float* __restrict__ a_sp, float* __restrict__ a_dp,
                      float* __restrict__ a_sc, float* __restrict__ a_dc,
                      float* __restrict__ selfP, float* __restrict__ selfC,
                      int N) {
  int gtid = blockIdx.x * blockDim.x + threadIdx.x;
  int gstride = gridDim.x * blockDim.x;
  int lane = threadIdx.x & 63;

  for (int q = gtid; q < S; q += gstride) {
    int n = s[q];
    bool won = (atomicCAS(&qid[n], -1, -2) == -1);
    unsigned long long mask = __ballot(won);
    if (mask != 0ull) {
      int leader = __builtin_ctzll(mask);
      int base = 0;
      if (lane == leader) base = atomicAdd(&counters[0], __popcll(mask));
      base = __shfl(base, leader);          // one same-address atomic per wave
      if (won) {
        int u = base + __popcll(mask & ((1ull << lane) - 1ull));
        uniq[u] = n;
        qid[n] = u;
      }
    }
  }

  const int slots = ((N + 1) >> 1) * 64;    // wave-uniform trip count
  for (int idx = gtid; idx < slots; idx += gstride) {
    int node = (idx >> 6) * 2 + ((idx & 63) >> 5);
    int c = idx & 31;                        // float4 chunk within row
    if (node >= N) continue;
    float4 x4 = ((const float4*)(emb + (size_t)node * D))[c];
    float4 v0 = ((const float4*)(v))[c];
    float4 v1 = ((const float4*)(v + D))[c];
    float4 v2 = ((const float4*)(v + 2 * D))[c];
    float4 v3 = ((const float4*)(v + 3 * D))[c];
    float s0 = x4.x * v0.x + x4.y * v0.y + x4.z * v0.z + x4.w * v0.w;
    float s1 = x4.x * v1.x + x4.y * v1.y + x4.z * v1.z + x4.w * v1.w;
    float s2 = x4.x * v2.x + x4.y * v2.y + x4.z * v2.z + x4.w * v2.w;
    float s3 = x4.x * v3.x + x4.y * v3.y + x4.z * v3.z + x4.w * v3.w;
#pragma unroll
    for (int o = 16; o > 0; o >>= 1) {
      s0 += __shfl_down(s0, o);
      s1 += __shfl_down(s1, o);
      s2 += __shfl_down(s2, o);
      s3 += __shfl_down(s3, o);
    }
    if (c == 0) {
      a_sp[node] = s0; a_dp[node] = s1; a_sc[node] = s2; a_dc[node] = s3;
      selfP[node] = __expf(lrelu(s0 + s1));
      selfC[node] = __expf(lrelu(s2 + s3));
    }
  }
}

// direct-bucket filter, single 1D grid-stride over all 3*E edges.
// GAT relations compute the edge weight here (edge-parallel, latency hidden)
// and accumulate the softmax denominator via float atomics:
// bkt[u*CAP+pos] = (src, w),  den[u] += w  (den covers ALL edges incl. overflow).
__global__ void __launch_bounds__(256) k_filter(
    const int* __restrict__ eiP, const int* __restrict__ eiC,
    const int* __restrict__ eiR, const int* __restrict__ qid,
    int2* __restrict__ bktP, int2* __restrict__ bktC, int* __restrict__ bktR,
    int* __restrict__ degP, int* __restrict__ degC, int* __restrict__ degR,
    float* __restrict__ denP, float* __restrict__ denC,
    const float* __restrict__ a_sp, const float* __restrict__ a_dp,
    const float* __restrict__ a_sc, const float* __restrict__ a_dc,
    int2* __restrict__ ovf, int* __restrict__ counters, int E) {
  int gtid = blockIdx.x * blockDim.x + threadIdx.x;
  int gstride = gridDim.x * blockDim.x;
  for (int e3 = gtid; e3 < 3 * E; e3 += gstride) {
    int rel = (e3 >= 2 * E) ? 2 : (e3 >= E) ? 1 : 0;
    int e = e3 - rel * E;
    const int* ei = (rel == 0) ? eiP : (rel == 1) ? eiC : eiR;
    int dst = ei[E + e];
    int u = qid[dst];
    if (u < 0) continue;
    int src = ei[e];
    int* deg = (rel == 0) ? degP : (rel == 1) ? degC : degR;
    int pos = atomicAdd(&deg[u], 1);
    if (rel == 2) {
      if (pos < CAP) {
        bktR[u * CAP + pos] = src;
      } else {
        int o = atomicAdd(&counters[6], 1);
        if (o < OVF_CAP) { int2 tt; tt.x = src; tt.y = u; ovf[2 * OVF_CAP + o] = tt; }
      }
    } else {
      const float* a_s = (rel == 0) ? a_sp : a_sc;
      const float* a_d = (rel == 0) ? a_dp : a_dc;
      float wgt = __expf(lrelu(a_s[src] + a_d[dst]));
      atomicAdd((rel == 0) ? &denP[u] : &denC[u], wgt);
      if (pos < CAP) {
        int2 tt; tt.x = src; tt.y = __builtin_bit_cast(int, wgt);
        ((rel == 0) ? bktP : bktC)[u * CAP + pos] = tt;
      } else {
        int o = atomicAdd(&counters[4 + rel], 1);
        if (o < OVF_CAP) { int2 tt; tt.x = src; tt.y = u; ovf[rel * OVF_CAP + o] = tt; }
      }
    }
  }
}

// fused gather+final: per 16-u tile, 8 waves x 2 u-rows each across all 3
// relations (weights precomputed: chain is bucket-load -> shfl -> emb gathers),
// stage z-rows into swizzled LDS A-fragments, then MFMA against packed Wcat.
// Gathers read emb directly as float2 (coalesced 512B rows, L3-resident).
// outU[u] = ([zP|zC|zR|x]@Wcat)/3 + bias/3.
__global__ void __launch_bounds__(512) k_fused(
    const int2* __restrict__ bktP, const int2* __restrict__ bktC,
    const int* __restrict__ bktR,
    const int* __restrict__ degP, const int* __restrict__ degC,
    const int* __restrict__ degR,
    const float* __restrict__ denP, const float* __restrict__ denC,
    const float* __restrict__ a_sp, const float* __restrict__ a_dp,
    const float* __restrict__ a_sc, const float* __restrict__ a_dc,
    const float* __restrict__ selfP, const float* __restrict__ selfC,
    const float* __restrict__ emb,
    const int* __restrict__ uniq, const int* __restrict__ counters,
    const int2* __restrict__ ovf, const float* __restrict__ vvec,
    const unsigned short* __restrict__ wpack, float* __restrict__ outU) {
  __shared__ __align__(16) unsigned short A_lds[16 * 64 * 8];   // 16 KB
  int U = counters[0];
  int u0 = blockIdx.x * 16;
  if (u0 >= U) return;
  int tid = threadIdx.x;
  int w = tid >> 6;
  int lane = tid & 63;
  const float2* er = (const float2*)emb;    // row stride = 64 float2

  int Lc[3];
#pragma unroll
  for (int r = 0; r < 3; ++r) {
    int L = counters[4 + r];
    Lc[r] = (L > OVF_CAP) ? OVF_CAP : L;
  }

#pragma unroll
  for (int t = 0; t < 2; ++t) {
    int m = 2 * w + t;
    int u = u0 + m;
    float2 z[4];
    if (u < U) {
      int n = uniq[u];
      float2 x2 = er[(size_t)n * 64 + lane];
#pragma unroll
      for (int r = 0; r < 3; ++r) {
        int dg = ((r == 0) ? degP : (r == 1) ? degC : degR)[u];
        int mc = (dg < CAP) ? dg : CAP;
        int srcl = 0;
        float wl = 0.f;
        if (r < 2) {
          if (lane < mc) {
            int2 sw_ = ((r == 0) ? bktP : bktC)[u * CAP + lane];
            srcl = sw_.x;
            wl = __builtin_bit_cast(float, sw_.y);
          }
        } else {
          if (lane < mc) { srcl = bktR[u * CAP + lane]; wl = 1.f; }
        }
        float2 a; a.x = 0.f; a.y = 0.f;
        int i = 0;
        for (; i + 4 <= mc; i += 4) {
          int s0 = __shfl(srcl, i),     s1 = __shfl(srcl, i + 1);
          int s2 = __shfl(srcl, i + 2), s3 = __shfl(srcl, i + 3);
          float w0 = __shfl(wl, i),     w1 = __shfl(wl, i + 1);
          float w2 = __shfl(wl, i + 2), w3 = __shfl(wl, i + 3);
          float2 r0 = er[(size_t)s0 * 64 + lane];
          float2 r1 = er[(size_t)s1 * 64 + lane];
          float2 r2 = er[(size_t)s2 * 64 + lane];
          float2 r3 = er[(size_t)s3 * 64 + lane];
          a.x += w0 * r0.x + w1 * r1.x + w2 * r2.x + w3 * r3.x;
          a.y += w0 * r0.y + w1 * r1.y + w2 * r2.y + w3 * r3.y;
        }
        for (; i < mc; ++i) {
          int si = __shfl(srcl, i);
          float wi = __shfl(wl, i);
          float2 rr = er[(size_t)si * 64 + lane];
          a.x += wi * rr.x;
          a.y += wi * rr.y;
        }
        // overflow numerator fixup (statistically never taken; den already full)
        if (dg > CAP) {
          const float* a_s = (r == 0) ? a_sp : a_sc;
          float adn = (r == 0) ? a_dp[n] : (r == 1) ? a_dc[n] : 0.f;
          for (int l = 0; l < Lc[r]; ++l) {
            int2 ov = ovf[r * OVF_CAP + l];
            if (ov.y == u) {
              float wv = 1.f;
              if (r < 2) wv = __expf(lrelu(a_s[ov.x] + adn));
              float2 rr = er[(size_t)ov.x * 64 + lane];
              a.x += wv * rr.x;
              a.y += wv * rr.y;
            }
          }
        }
        if (r == 2) {
          float dgc = (float)dg; if (dgc < 1.f) dgc = 1.f;
          float rc = 1.f / dgc;
          a.x *= rc; a.y *= rc;
        }
        z[r] = a;
      }
      float wP = selfP[n];
      float rP = 1.f / (denP[u] + wP);
      float wC = selfC[n];
      float rC = 1.f / (denC[u] + wC);
      z[0].x = (z[0].x + wP * x2.x) * rP; z[0].y = (z[0].y + wP * x2.y) * rP;
      z[1].x = (z[1].x + wC * x2.x) * rC; z[1].y = (z[1].y + wC * x2.y) * rC;
      z[3] = x2;
    } else {
      z[0].x = 0.f; z[0].y = 0.f; z[1] = z[0]; z[2] = z[0]; z[3] = z[0];
    }
    // LDS A-fragment write (swizzled): columns c=2*lane, 2*lane+1 of operand o
    int ktc = lane >> 4;
    int q = (lane >> 2) & 3;
    int j0 = 2 * (lane & 3);
#pragma unroll
    for (int o = 0; o < 4; ++o) {
      int kt = o * 4 + ktc;
      unsigned pk = ((unsigned)f2bf(z[o].x)) | (((unsigned)f2bf(z[o].y)) << 16);
      int off = ((kt * 64 + q * 16 + m) * 8 + j0) * 2;
      *(unsigned*)((char*)A_lds + swz(off)) = pk;
    }
  }
  __syncthreads();

  f32x4 acc = {0.f, 0.f, 0.f, 0.f};
  const bf16x8* wp = (const bf16x8*)wpack;
#pragma unroll
  for (int kt = 0; kt < 16; ++kt) {
    bf16x8 a = *(const bf16x8*)((const char*)A_lds + swz((kt * 64 + lane) * 16));
    bf16x8 b = wp[(kt * 8 + w) * 64 + lane];
    acc = __builtin_amdgcn_mfma_f32_16x16x32_bf16(a, b, acc, 0, 0, 0);
  }

  int col = w * 16 + (lane & 15);
  int r0 = (lane >> 4) * 4;
  float bv = vvec[4 * D + col] * (1.f / 3.f);
#pragma unroll
  for (int reg = 0; reg < 4; ++reg) {
    int u = u0 + r0 + reg;
    if (u < U) outU[(size_t)u * D + col] = acc[reg] * (1.f / 3.f) + bv;
  }
}

// pure gather, float4-vectorized, grid-strided (bias and /3 folded into outU)
__global__ void k_gather(const int* __restrict__ s, const int* __restrict__ qid,
                         const float4* __restrict__ outU4, float4* __restrict__ out4,
                         int S) {
  int gtid = blockIdx.x * blockDim.x + threadIdx.x;
  int gstride = gridDim.x * blockDim.x;
  for (int idx = gtid; idx < S * 32; idx += gstride) {
    int i = idx >> 5;
    int c = idx & 31;
    int u = qid[s[i]];
    out4[idx] = outU4[(size_t)u * 32 + c];
  }
}

// ---------------- launch ----------------

extern "C" void kernel_launch(void* const* d_in, const int* in_sizes, int n_in,
                              void* d_out, int out_size, void* d_ws, size_t ws_size,
                              hipStream_t stream) {
  const int*   s   = (const int*)d_in[0];
  const int*   eip = (const int*)d_in[3];
  const int*   eic = (const int*)d_in[4];
  const int*   eir = (const int*)d_in[5];
  const float* emb = (const float*)d_in[6];
  const float* Wp  = (const float*)d_in[7];
  const float* asp = (const float*)d_in[8];
  const float* adp = (const float*)d_in[9];
  const float* bp  = (const float*)d_in[10];
  const float* Wc  = (const float*)d_in[11];
  const float* asc = (const float*)d_in[12];
  const float* adc = (const float*)d_in[13];
  const float* bc  = (const float*)d_in[14];
  const float* Wl  = (const float*)d_in[15];
  const float* bl  = (const float*)d_in[16];
  const float* Wr  = (const float*)d_in[17];
  float* out = (float*)d_out;

  const int S = in_sizes[0];
  const int E = in_sizes[3] / 2;
  const int N = in_sizes[6] / D;

  char* base = (char*)d_ws;
  size_t off = 0;
  auto carve = [&](size_t bytes) -> char* {
    char* q = base + off;
    off += (bytes + 255) & ~(size_t)255;
    return q;
  };
  float*    a_sp     = (float*)carve((size_t)N * 4);
  float*    a_dp     = (float*)carve((size_t)N * 4);
  float*    a_sc     = (float*)carve((size_t)N * 4);
  float*    a_dc     = (float*)carve((size_t)N * 4);
  float*    selfP    = (float*)carve((size_t)N * 4);
  float*    selfC    = (float*)carve((size_t)N * 4);
  int*      qid      = (int*)carve((size_t)N * 4);
  int*      uniq     = (int*)carve((size_t)S * 4);
  int*      counters = (int*)carve(64);    // [0]=U [4..6]=overflow counts
  float*    vvec     = (float*)carve(5 * D * 4);
  unsigned short* wpack = (unsigned short*)carve((size_t)16 * 8 * 64 * 8 * 2);  // 128 KB
  float*    outU     = (float*)carve((size_t)S * D * 4);
  int*      degP     = (int*)carve((size_t)S * 4);      // degP/C/R + denP/C contiguous
  int*      degC     = (int*)carve((size_t)S * 4);
  int*      degR     = (int*)carve((size_t)S * 4);
  float*    denP     = (float*)carve((size_t)S * 4);
  float*    denC     = (float*)carve((size_t)S * 4);
  int2*     bktP     = (int2*)carve((size_t)S * CAP * 8);   // (src, w) pairs
  int2*     bktC     = (int2*)carve((size_t)S * CAP * 8);
  int*      bktR     = (int*)carve((size_t)S * CAP * 4);
  int2*     ovf      = (int2*)carve((size_t)3 * OVF_CAP * 8);
  (void)ws_size; (void)n_in; (void)out_size;

  k_setup<<<256, 256, 0, stream>>>(Wp, asp, adp, Wc, asc, adc, bp, bc, bl, Wl, Wr,
                                   vvec, wpack, qid, counters, degP, N, 5 * S);

  k_pre<<<2048, 256, 0, stream>>>(s, qid, uniq, counters, S,
                                  emb, vvec, a_sp, a_dp, a_sc, a_dc,
                                  selfP, selfC, N);

  k_filter<<<2048, 256, 0, stream>>>(
      eip, eic, eir, qid, bktP, bktC, bktR, degP, degC, degR, denP, denC,
      a_sp, a_dp, a_sc, a_dc, ovf, counters, E);

  k_fused<<<(S + 15) / 16, 512, 0, stream>>>(
      bktP, bktC, bktR, degP, degC, degR, denP, denC,
      a_sp, a_dp, a_sc, a_dc, selfP, selfC, emb, uniq, counters, ovf,
      vvec, wpack, outU);

  k_gather<<<512, 256, 0, stream>>>(s, qid, (const float4*)outU, (float4*)out, S);
}

// Round 5
// 199.696 us; speedup vs baseline: 1.9318x; 1.0485x over previous
//
#include <hip/hip_runtime.h>

#define D 128
#define CAP 64
#define OVF_CAP 1024

typedef short bf16x8 __attribute__((ext_vector_type(8)));
typedef float f32x4 __attribute__((ext_vector_type(4)));

__device__ __forceinline__ unsigned short f2bf(float f) {
  unsigned u = __builtin_bit_cast(unsigned, f);
  unsigned r = (u + 0x7fffu + ((u >> 16) & 1u)) >> 16;
  return (unsigned short)r;
}
__device__ __forceinline__ float bflo(unsigned r) {
  return __builtin_bit_cast(float, r << 16);
}
__device__ __forceinline__ float bfhi(unsigned r) {
  return __builtin_bit_cast(float, r & 0xffff0000u);
}
__device__ __forceinline__ float lrelu(float t) {
  return t >= 0.f ? t : 0.2f * t;
}
// LDS byte-offset swizzle: XOR bits 8-10 into bits 4-6 (write side spreads a
// fixed row's 64 lanes over all banks; read stays full-coverage b128).
__device__ __forceinline__ int swz(int b) { return b ^ (((b >> 8) & 7) << 4); }

// ---------------- kernels ----------------

// setup: qid=-1, deg/den=0, counters=0, pack Wcat->bf16 fragments, calc_v
// (block 0, coalesced: half-wave per row, width-32 shfl reduce)
__global__ void k_setup(const float* __restrict__ Wp, const float* __restrict__ asp,
                        const float* __restrict__ adp, const float* __restrict__ Wc,
                        const float* __restrict__ asc, const float* __restrict__ adc,
                        const float* __restrict__ bp, const float* __restrict__ bc,
                        const float* __restrict__ bl, const float* __restrict__ Wl,
                        const float* __restrict__ Wr,
                        float* __restrict__ v, unsigned short* __restrict__ wpack,
                        int* __restrict__ qid, int* __restrict__ counters,
                        int* __restrict__ deg5, int N, int S5) {
  int i = blockIdx.x * blockDim.x + threadIdx.x;
  int stride = gridDim.x * blockDim.x;
  for (int k = i; k < N; k += stride) qid[k] = -1;
  for (int k = i; k < S5; k += stride) deg5[k] = 0;   // degP/C/R + denP/denC (0.0f)
  if (i < 16) counters[i] = 0;

  // wpack[((kt*8+nt)*64+lane)*8+j] = Wcat[kt*32+(lane>>4)*8+j][nt*16+(lane&15)]
  for (int idx = i; idx < 16 * 8 * 64 * 8; idx += stride) {
    int j    = idx & 7;
    int lane = (idx >> 3) & 63;
    int nt   = (idx >> 9) & 7;
    int kt   = idx >> 12;
    int o = kt >> 2;
    int c = (kt & 3) * 32 + (lane >> 4) * 8 + j;
    int n = nt * 16 + (lane & 15);
    const float* W = (o == 0) ? Wp : (o == 1) ? Wc : (o == 2) ? Wl : Wr;
    wpack[idx] = f2bf(W[c * D + n]);
  }

  if (blockIdx.x == 0) {
    int hw = threadIdx.x >> 5;       // half-wave id 0..7
    int ln = threadIdx.x & 31;
    float4 as4p = ((const float4*)asp)[ln];
    float4 ad4p = ((const float4*)adp)[ln];
    float4 as4c = ((const float4*)asc)[ln];
    float4 ad4c = ((const float4*)adc)[ln];
    for (int k = hw; k < D; k += 8) {
      float4 wp4 = ((const float4*)(Wp + (size_t)k * D))[ln];  // coalesced row
      float4 wc4 = ((const float4*)(Wc + (size_t)k * D))[ln];
      float s0 = wp4.x * as4p.x + wp4.y * as4p.y + wp4.z * as4p.z + wp4.w * as4p.w;
      float s1 = wp4.x * ad4p.x + wp4.y * ad4p.y + wp4.z * ad4p.z + wp4.w * ad4p.w;
      float s2 = wc4.x * as4c.x + wc4.y * as4c.y + wc4.z * as4c.z + wc4.w * as4c.w;
      float s3 = wc4.x * ad4c.x + wc4.y * ad4c.y + wc4.z * ad4c.z + wc4.w * ad4c.w;
#pragma unroll
      for (int o = 16; o > 0; o >>= 1) {
        s0 += __shfl_down(s0, o, 32);
        s1 += __shfl_down(s1, o, 32);
        s2 += __shfl_down(s2, o, 32);
        s3 += __shfl_down(s3, o, 32);
      }
      if (ln == 0) {
        v[k] = s0; v[D + k] = s1; v[2 * D + k] = s2; v[3 * D + k] = s3;
      }
    }
    if (threadIdx.x < D) {
      int k = threadIdx.x;
      v[4 * D + k] = bp[k] + bc[k] + bl[k];
    }
  }
}

// Canonical-slot assignment (single CAS: qid[n] = first query slot claiming n)
// + attention scalars + self-loop weights + bf16 emb copy.
// Grid-strided; one wave handles TWO nodes: 32 lanes x float4 per node row.
__global__ void k_pre(const int* __restrict__ s, int* __restrict__ qid, int S,
                      const float* __restrict__ emb, const float* __restrict__ v,
                      float* __restrict__ a_sp, float* __restrict__ a_dp,
                      float* __restrict__ a_sc, float* __restrict__ a_dc,
                      float* __restrict__ selfP, float* __restrict__ selfC,
                      unsigned* __restrict__ ebf, int N) {
  int gtid = blockIdx.x * blockDim.x + threadIdx.x;
  int gstride = gridDim.x * blockDim.x;

  for (int q = gtid; q < S; q += gstride) {
    int n = s[q];
    atomicCAS(&qid[n], -1, q);     // winner's slot becomes canonical for node n
  }

  const int slots = ((N + 1) >> 1) * 64;    // wave-uniform trip count
  for (int idx = gtid; idx < slots; idx += gstride) {
    int node = (idx >> 6) * 2 + ((idx & 63) >> 5);
    int c = idx & 31;                        // float4 chunk within row
    if (node >= N) continue;
    float4 x4 = ((const float4*)(emb + (size_t)node * D))[c];
    uint2 p;
    p.x = ((unsigned)f2bf(x4.x)) | (((unsigned)f2bf(x4.y)) << 16);
    p.y = ((unsigned)f2bf(x4.z)) | (((unsigned)f2bf(x4.w)) << 16);
    ((uint2*)ebf)[(size_t)node * 32 + c] = p;
    float4 v0 = ((const float4*)(v))[c];
    float4 v1 = ((const float4*)(v + D))[c];
    float4 v2 = ((const float4*)(v + 2 * D))[c];
    float4 v3 = ((const float4*)(v + 3 * D))[c];
    float s0 = x4.x * v0.x + x4.y * v0.y + x4.z * v0.z + x4.w * v0.w;
    float s1 = x4.x * v1.x + x4.y * v1.y + x4.z * v1.z + x4.w * v1.w;
    float s2 = x4.x * v2.x + x4.y * v2.y + x4.z * v2.z + x4.w * v2.w;
    float s3 = x4.x * v3.x + x4.y * v3.y + x4.z * v3.z + x4.w * v3.w;
#pragma unroll
    for (int o = 16; o > 0; o >>= 1) {
      s0 += __shfl_down(s0, o);
      s1 += __shfl_down(s1, o);
      s2 += __shfl_down(s2, o);
      s3 += __shfl_down(s3, o);
    }
    if (c == 0) {
      a_sp[node] = s0; a_dp[node] = s1; a_sc[node] = s2; a_dc[node] = s3;
      selfP[node] = __expf(lrelu(s0 + s1));
      selfC[node] = __expf(lrelu(s2 + s3));
    }
  }
}

// direct-bucket filter (blockIdx.y = relation), buckets keyed by canonical slot.
// GAT relations compute the edge weight here and accumulate the softmax
// denominator via float atomics: bkt[u*CAP+pos]=(src,w), den[u]+=w (all edges).
__global__ void __launch_bounds__(256) k_filter(
    const int* __restrict__ eiP, const int* __restrict__ eiC,
    const int* __restrict__ eiR, const int* __restrict__ qid,
    int2* __restrict__ bktP, int2* __restrict__ bktC, int* __restrict__ bktR,
    int* __restrict__ degP, int* __restrict__ degC, int* __restrict__ degR,
    float* __restrict__ denP, float* __restrict__ denC,
    const float* __restrict__ a_sp, const float* __restrict__ a_dp,
    const float* __restrict__ a_sc, const float* __restrict__ a_dc,
    int2* __restrict__ ovf, int* __restrict__ counters, int E) {
  int rel = blockIdx.y;
  const int* ei = (rel == 0) ? eiP : (rel == 1) ? eiC : eiR;
  int e = blockIdx.x * 256 + threadIdx.x;
  if (e >= E) return;
  int dst = ei[E + e];
  int u = qid[dst];
  if (u < 0) return;
  int src = ei[e];
  int* deg = (rel == 0) ? degP : (rel == 1) ? degC : degR;
  int pos = atomicAdd(&deg[u], 1);
  if (rel == 2) {
    if (pos < CAP) {
      bktR[u * CAP + pos] = src;
    } else {
      int o = atomicAdd(&counters[6], 1);
      if (o < OVF_CAP) { int2 tt; tt.x = src; tt.y = u; ovf[2 * OVF_CAP + o] = tt; }
    }
  } else {
    const float* a_s = (rel == 0) ? a_sp : a_sc;
    const float* a_d = (rel == 0) ? a_dp : a_dc;
    float wgt = __expf(lrelu(a_s[src] + a_d[dst]));
    atomicAdd((rel == 0) ? &denP[u] : &denC[u], wgt);
    if (pos < CAP) {
      int2 tt; tt.x = src; tt.y = __builtin_bit_cast(int, wgt);
      ((rel == 0) ? bktP : bktC)[u * CAP + pos] = tt;
    } else {
      int o = atomicAdd(&counters[4 + rel], 1);
      if (o < OVF_CAP) { int2 tt; tt.x = src; tt.y = u; ovf[rel * OVF_CAP + o] = tt; }
    }
  }
}

// fused gather+final, SLOT-DIRECT: per 16-slot tile, 8 waves x 2 rows each.
// Row i uses node n=s[i] and canonical slot u=qid[n] (bucket/deg/den reads);
// duplicates recompute (~8% extra) but k_gather + outU round-trip vanish.
// Stages z-rows into swizzled LDS A-fragments, MFMA against packed Wcat,
// writes out[i] = ([zP|zC|zR|x]@Wcat)/3 + bias/3 directly.
__global__ void __launch_bounds__(512, 4) k_fused(
    const int* __restrict__ s,
    const int2* __restrict__ bktP, const int2* __restrict__ bktC,
    const int* __restrict__ bktR,
    const int* __restrict__ degP, const int* __restrict__ degC,
    const int* __restrict__ degR,
    const float* __restrict__ denP, const float* __restrict__ denC,
    const float* __restrict__ a_sp, const float* __restrict__ a_dp,
    const float* __restrict__ a_sc, const float* __restrict__ a_dc,
    const float* __restrict__ selfP, const float* __restrict__ selfC,
    const unsigned* __restrict__ ebf, const float* __restrict__ emb,
    const int* __restrict__ qid, const int* __restrict__ counters,
    const int2* __restrict__ ovf, const float* __restrict__ vvec,
    const unsigned short* __restrict__ wpack, float* __restrict__ out, int S) {
  __shared__ __align__(16) unsigned short A_lds[16 * 64 * 8];   // 16 KB
  int i0 = blockIdx.x * 16;
  int tid = threadIdx.x;
  int w = tid >> 6;
  int lane = tid & 63;

  int Lc[3];
#pragma unroll
  for (int r = 0; r < 3; ++r) {
    int L = counters[4 + r];
    Lc[r] = (L > OVF_CAP) ? OVF_CAP : L;
  }

#pragma unroll
  for (int t = 0; t < 2; ++t) {
    int m = 2 * w + t;
    int i = i0 + m;                        // slot; always < S (S multiple of 16)
    int n = s[i];
    int u = qid[n];                        // canonical slot (>=0: n was queried)
    float2 x2 = ((const float2*)(emb + (size_t)n * D))[lane];
    float2 z[4];
#pragma unroll
    for (int r = 0; r < 3; ++r) {
      int dg = ((r == 0) ? degP : (r == 1) ? degC : degR)[u];
      int mc = (dg < CAP) ? dg : CAP;
      int srcl = 0;
      float wl = 0.f;
      if (r < 2) {
        if (lane < mc) {
          int2 sw_ = ((r == 0) ? bktP : bktC)[u * CAP + lane];
          srcl = sw_.x;
          wl = __builtin_bit_cast(float, sw_.y);
        }
      } else {
        if (lane < mc) { srcl = bktR[u * CAP + lane]; wl = 1.f; }
      }
      float2 a; a.x = 0.f; a.y = 0.f;
      int i2 = 0;
      for (; i2 + 4 <= mc; i2 += 4) {
        int s0 = __shfl(srcl, i2),     s1 = __shfl(srcl, i2 + 1);
        int s2 = __shfl(srcl, i2 + 2), s3 = __shfl(srcl, i2 + 3);
        float w0 = __shfl(wl, i2),     w1 = __shfl(wl, i2 + 1);
        float w2 = __shfl(wl, i2 + 2), w3 = __shfl(wl, i2 + 3);
        unsigned r0 = ebf[(size_t)s0 * 64 + lane];
        unsigned r1 = ebf[(size_t)s1 * 64 + lane];
        unsigned r2 = ebf[(size_t)s2 * 64 + lane];
        unsigned r3 = ebf[(size_t)s3 * 64 + lane];
        a.x += w0 * bflo(r0) + w1 * bflo(r1) + w2 * bflo(r2) + w3 * bflo(r3);
        a.y += w0 * bfhi(r0) + w1 * bfhi(r1) + w2 * bfhi(r2) + w3 * bfhi(r3);
      }
      for (; i2 < mc; ++i2) {
        int si = __shfl(srcl, i2);
        float wi = __shfl(wl, i2);
        unsigned rr = ebf[(size_t)si * 64 + lane];
        a.x += wi * bflo(rr);
        a.y += wi * bfhi(rr);
      }
      // overflow numerator fixup (statistically never taken; den already full)
      if (dg > CAP) {
        const float* a_s = (r == 0) ? a_sp : a_sc;
        float adn = (r == 0) ? a_dp[n] : (r == 1) ? a_dc[n] : 0.f;
        for (int l = 0; l < Lc[r]; ++l) {
          int2 ov = ovf[r * OVF_CAP + l];
          if (ov.y == u) {
            float wv = 1.f;
            if (r < 2) wv = __expf(lrelu(a_s[ov.x] + adn));
            unsigned rr = ebf[(size_t)ov.x * 64 + lane];
            a.x += wv * bflo(rr);
            a.y += wv * bfhi(rr);
          }
        }
      }
      if (r == 2) {
        float dgc = (float)dg; if (dgc < 1.f) dgc = 1.f;
        float rc = 1.f / dgc;
        a.x *= rc; a.y *= rc;
      }
      z[r] = a;
    }
    float wP = selfP[n];
    float rP = 1.f / (denP[u] + wP);
    float wC = selfC[n];
    float rC = 1.f / (denC[u] + wC);
    z[0].x = (z[0].x + wP * x2.x) * rP; z[0].y = (z[0].y + wP * x2.y) * rP;
    z[1].x = (z[1].x + wC * x2.x) * rC; z[1].y = (z[1].y + wC * x2.y) * rC;
    z[3] = x2;
    // LDS A-fragment write (swizzled): columns c=2*lane, 2*lane+1 of operand o
    int ktc = lane >> 4;
    int q = (lane >> 2) & 3;
    int j0 = 2 * (lane & 3);
#pragma unroll
    for (int o = 0; o < 4; ++o) {
      int kt = o * 4 + ktc;
      unsigned pk = ((unsigned)f2bf(z[o].x)) | (((unsigned)f2bf(z[o].y)) << 16);
      int off = ((kt * 64 + q * 16 + m) * 8 + j0) * 2;
      *(unsigned*)((char*)A_lds + swz(off)) = pk;
    }
  }
  __syncthreads();

  f32x4 acc = {0.f, 0.f, 0.f, 0.f};
  const bf16x8* wp = (const bf16x8*)wpack;
#pragma unroll
  for (int kt = 0; kt < 16; ++kt) {
    bf16x8 a = *(const bf16x8*)((const char*)A_lds + swz((kt * 64 + lane) * 16));
    bf16x8 b = wp[(kt * 8 + w) * 64 + lane];
    acc = __builtin_amdgcn_mfma_f32_16x16x32_bf16(a, b, acc, 0, 0, 0);
  }

  int col = w * 16 + (lane & 15);
  int r0 = (lane >> 4) * 4;
  float bv = vvec[4 * D + col] * (1.f / 3.f);
#pragma unroll
  for (int reg = 0; reg < 4; ++reg) {
    int i = i0 + r0 + reg;
    if (i < S) out[(size_t)i * D + col] = acc[reg] * (1.f / 3.f) + bv;
  }
}

// ---------------- launch ----------------

extern "C" void kernel_launch(void* const* d_in, const int* in_sizes, int n_in,
                              void* d_out, int out_size, void* d_ws, size_t ws_size,
                              hipStream_t stream) {
  const int*   s   = (const int*)d_in[0];
  const int*   eip = (const int*)d_in[3];
  const int*   eic = (const int*)d_in[4];
  const int*   eir = (const int*)d_in[5];
  const float* emb = (const float*)d_in[6];
  const float* Wp  = (const float*)d_in[7];
  const float* asp = (const float*)d_in[8];
  const float* adp = (const float*)d_in[9];
  const float* bp  = (const float*)d_in[10];
  const float* Wc  = (const float*)d_in[11];
  const float* asc = (const float*)d_in[12];
  const float* adc = (const float*)d_in[13];
  const float* bc  = (const float*)d_in[14];
  const float* Wl  = (const float*)d_in[15];
  const float* bl  = (const float*)d_in[16];
  const float* Wr  = (const float*)d_in[17];
  float* out = (float*)d_out;

  const int S = in_sizes[0];
  const int E = in_sizes[3] / 2;
  const int N = in_sizes[6] / D;

  char* base = (char*)d_ws;
  size_t off = 0;
  auto carve = [&](size_t bytes) -> char* {
    char* q = base + off;
    off += (bytes + 255) & ~(size_t)255;
    return q;
  };
  float*    a_sp     = (float*)carve((size_t)N * 4);
  float*    a_dp     = (float*)carve((size_t)N * 4);
  float*    a_sc     = (float*)carve((size_t)N * 4);
  float*    a_dc     = (float*)carve((size_t)N * 4);
  float*    selfP    = (float*)carve((size_t)N * 4);
  float*    selfC    = (float*)carve((size_t)N * 4);
  int*      qid      = (int*)carve((size_t)N * 4);
  unsigned* ebf      = (unsigned*)carve((size_t)N * 64 * 4);   // 25.6 MB bf16 emb
  int*      counters = (int*)carve(64);    // [4..6]=overflow counts
  float*    vvec     = (float*)carve(5 * D * 4);
  unsigned short* wpack = (unsigned short*)carve((size_t)16 * 8 * 64 * 8 * 2);  // 128 KB
  int*      degP     = (int*)carve((size_t)S * 4);      // degP/C/R + denP/C contiguous
  int*      degC     = (int*)carve((size_t)S * 4);
  int*      degR     = (int*)carve((size_t)S * 4);
  float*    denP     = (float*)carve((size_t)S * 4);
  float*    denC     = (float*)carve((size_t)S * 4);
  int2*     bktP     = (int2*)carve((size_t)S * CAP * 8);   // (src, w) pairs
  int2*     bktC     = (int2*)carve((size_t)S * CAP * 8);
  int*      bktR     = (int*)carve((size_t)S * CAP * 4);
  int2*     ovf      = (int2*)carve((size_t)3 * OVF_CAP * 8);
  (void)ws_size; (void)n_in; (void)out_size;

  k_setup<<<256, 256, 0, stream>>>(Wp, asp, adp, Wc, asc, adc, bp, bc, bl, Wl, Wr,
                                   vvec, wpack, qid, counters, degP, N, 5 * S);

  k_pre<<<2048, 256, 0, stream>>>(s, qid, S, emb, vvec, a_sp, a_dp, a_sc, a_dc,
                                  selfP, selfC, ebf, N);

  k_filter<<<dim3((E + 255) / 256, 3), 256, 0, stream>>>(
      eip, eic, eir, qid, bktP, bktC, bktR, degP, degC, degR, denP, denC,
      a_sp, a_dp, a_sc, a_dc, ovf, counters, E);

  k_fused<<<(S + 15) / 16, 512, 0, stream>>>(
      s, bktP, bktC, bktR, degP, degC, degR, denP, denC,
      a_sp, a_dp, a_sc, a_dc, selfP, selfC, ebf, emb, qid, counters, ovf,
      vvec, wpack, out, S);
}